// Round 5
// baseline (309.915 us; speedup 1.0000x reference)
//
#include <hip/hip_runtime.h>

#define DF 256
#define HID 16
#define WB 512          // sort slices == mega grid size
#define TPB 512         // threads per block
#define NBLK 512        // mega grid
#define PBITS 8         // partition = 256 nodes
#define PMAX 511        // P+1 must fit in TPB-wide scan

// ---------------- grid barrier (device-scope, sense via monotonic counter) ----------------
__device__ __forceinline__ void gbar(unsigned* cnt, unsigned target) {
    __syncthreads();
    if (threadIdx.x == 0) {
        __hip_atomic_fetch_add(cnt, 1u, __ATOMIC_RELEASE, __HIP_MEMORY_SCOPE_AGENT);
        unsigned it = 0;
        while (__hip_atomic_load(cnt, __ATOMIC_ACQUIRE, __HIP_MEMORY_SCOPE_AGENT) < target
               && ++it < (1u << 24))
            __builtin_amdgcn_s_sleep(2);
    }
    __syncthreads();
}

// ---------------- megakernel: sort + sval | deg/dinv/tval | reduce/out ----------------
extern "C" __global__ void __launch_bounds__(TPB, 4)
mega_kernel(const float* __restrict__ x, const int* __restrict__ src, const int* __restrict__ dst,
            const float* __restrict__ Wm, const float* __restrict__ b_conv,
            const float* __restrict__ W_fc, const float* __restrict__ b_fc,
            float* __restrict__ sv, float* __restrict__ dinv, float* __restrict__ tval,
            unsigned* __restrict__ runStart, unsigned* __restrict__ sorted,
            unsigned* __restrict__ bars, float* __restrict__ out,
            int N, int E, int P, int Epw) {
    extern __shared__ unsigned smem[];
    // ---- P1a: block-local counting sort of slice w by dst partition ----
    unsigned* pack  = smem;               // Epw
    unsigned* sortl = pack + Epw;         // Epw (scan scratch + sorted slice)
    unsigned* offs  = sortl + Epw;        // P+1
    unsigned* cur   = offs + (P + 1);     // P
    unsigned short* keyp = (unsigned short*)(cur + P);  // Epw

    const int w = blockIdx.x;
    const int e0 = w * Epw;
    int m = E - e0; if (m > Epw) m = Epw; if (m < 0) m = 0;

    for (int i = threadIdx.x; i < P; i += TPB) cur[i] = 0;
    __syncthreads();
    for (int i = threadIdx.x; i < m; i += TPB) {
        unsigned s = (unsigned)src[e0 + i];
        unsigned d = (unsigned)dst[e0 + i];
        keyp[i] = (unsigned short)(d >> PBITS);
        pack[i] = (s << PBITS) | (d & 255u);
        atomicAdd(&cur[d >> PBITS], 1u);
    }
    __syncthreads();
    {   // exclusive scan of cur[0..P) (TPB-wide Hillis; sortl as scratch, Epw >= TPB)
        int t = threadIdx.x;
        unsigned v = (t < P) ? cur[t] : 0u;
        sortl[t] = v;
        __syncthreads();
        for (int off = 1; off < TPB; off <<= 1) {
            unsigned u = (t >= off) ? sortl[t - off] : 0u;
            __syncthreads();
            sortl[t] += u;
            __syncthreads();
        }
        if (t < P) offs[t] = sortl[t] - v;
        if (t == 0) offs[P] = (unsigned)m;
    }
    __syncthreads();
    for (int i = threadIdx.x; i < P; i += TPB) cur[i] = offs[i];
    __syncthreads();
    for (int i = threadIdx.x; i < m; i += TPB) {
        unsigned slot = atomicAdd(&cur[keyp[i]], 1u);
        sortl[slot] = pack[i];
    }
    __syncthreads();
    for (int i = threadIdx.x; i < m; i += TPB) sorted[(size_t)e0 + i] = sortl[i];
    for (int p = threadIdx.x; p <= P; p += TPB) runStart[(size_t)p * WB + w] = offs[p];

    // ---- P1b: sval rows (w-vector in registers, per wave) ----
    {
        int lane = threadIdx.x & 63;
        int wid  = threadIdx.x >> 6;  // 0..7
        float a0 = 0.f, a1 = 0.f, a2 = 0.f, a3 = 0.f;
        const float* wrow = Wm + (size_t)(lane * 4) * HID;
#pragma unroll
        for (int j = 0; j < HID; ++j) {
            float f = W_fc[j];
            a0 += wrow[j] * f;
            a1 += wrow[HID + j] * f;
            a2 += wrow[2 * HID + j] * f;
            a3 += wrow[3 * HID + j] * f;
        }
        for (int row = blockIdx.x * 8 + wid; row < N; row += NBLK * 8) {
            float4 xv = reinterpret_cast<const float4*>(x + (size_t)row * DF)[lane];
            float acc = xv.x * a0 + xv.y * a1 + xv.z * a2 + xv.w * a3;
#pragma unroll
            for (int off = 32; off > 0; off >>= 1) acc += __shfl_xor(acc, off, 64);
            if (lane == 0) sv[row] = acc;
        }
    }

    gbar(&bars[0], NBLK);

    // ---- P2: per-partition degree -> dinv, tval ----
    {
        unsigned* dc = smem;  // 256 u32 (sort arrays dead)
        for (int p = blockIdx.x; p < P; p += NBLK) {
            if (threadIdx.x < 256) dc[threadIdx.x] = 0u;
            __syncthreads();
            unsigned s0 = runStart[(size_t)p * WB + threadIdx.x];
            unsigned s1 = runStart[(size_t)(p + 1) * WB + threadIdx.x];
            const unsigned* base = sorted + (size_t)threadIdx.x * Epw;
            for (unsigned j = s0; j < s1; ++j) atomicAdd(&dc[base[j] & 255u], 1u);
            __syncthreads();
            if (threadIdx.x < 256) {
                int i = (p << PBITS) + threadIdx.x;
                if (i < N) {
                    float deg = 1.0f + (float)dc[threadIdx.x];
                    float di = rsqrtf(deg);
                    dinv[i] = di;
                    tval[i] = sv[i] * di;
                }
            }
            __syncthreads();
        }
    }

    gbar(&bars[1], NBLK);

    // ---- P3: per-partition reduce; final out = sv*di^2 + c + di*acc ----
    {
        float* facc = (float*)smem;
        float cterm;
        {
            float c = 0.f;
#pragma unroll
            for (int j = 0; j < HID; ++j) c += b_conv[j] * W_fc[j];
            cterm = c + b_fc[0];
        }
        for (int p = blockIdx.x; p < P; p += NBLK) {
            if (threadIdx.x < 256) facc[threadIdx.x] = 0.f;
            __syncthreads();
            unsigned s0 = runStart[(size_t)p * WB + threadIdx.x];
            unsigned s1 = runStart[(size_t)(p + 1) * WB + threadIdx.x];
            const unsigned* base = sorted + (size_t)threadIdx.x * Epw;
            for (unsigned j = s0; j < s1; ++j) {
                unsigned e = base[j];
                atomicAdd(&facc[e & 255u], tval[e >> PBITS]);
            }
            __syncthreads();
            if (threadIdx.x < 256) {
                int i = (p << PBITS) + threadIdx.x;
                if (i < N) {
                    float di = dinv[i];
                    out[i] = sv[i] * di * di + cterm + di * facc[threadIdx.x];
                }
            }
            __syncthreads();
        }
    }
}

// ---------------- round-4 fallback path (proven correct) ----------------
__global__ void sval_kernel(const float* __restrict__ x, const float* __restrict__ Wm,
                            const float* __restrict__ W_fc, float* __restrict__ sv, int N) {
    __shared__ float wl[DF];
    int k = threadIdx.x;
    float a = 0.f;
#pragma unroll
    for (int j = 0; j < HID; ++j) a += Wm[k * HID + j] * W_fc[j];
    wl[k] = a;
    __syncthreads();
    int lane = threadIdx.x & 63;
    int wid = threadIdx.x >> 6;
    float4 wv = reinterpret_cast<const float4*>(wl)[lane];
    for (int row = blockIdx.x * 4 + wid; row < N; row += gridDim.x * 4) {
        float4 xv = reinterpret_cast<const float4*>(x + (size_t)row * DF)[lane];
        float acc = xv.x * wv.x + xv.y * wv.y + xv.z * wv.z + xv.w * wv.w;
#pragma unroll
        for (int off = 32; off > 0; off >>= 1) acc += __shfl_xor(acc, off, 64);
        if (lane == 0) sv[row] = acc;
    }
}
__global__ void fb_count(const int* __restrict__ dst, unsigned* __restrict__ cnt, int E) {
    int stride = gridDim.x * blockDim.x;
    for (int e = blockIdx.x * blockDim.x + threadIdx.x; e < E; e += stride)
        atomicAdd(&cnt[dst[e]], 1u);
}
__global__ void fb_node(const unsigned* __restrict__ cnt, const float* __restrict__ sv,
                        const float* __restrict__ b_conv, const float* __restrict__ W_fc,
                        const float* __restrict__ b_fc, float* __restrict__ dinv,
                        float* __restrict__ tval, float* __restrict__ out, int N) {
    int i = blockIdx.x * blockDim.x + threadIdx.x;
    if (i < N) {
        float c = 0.f;
#pragma unroll
        for (int j = 0; j < HID; ++j) c += b_conv[j] * W_fc[j];
        float deg = 1.0f + (float)cnt[i];
        float di = rsqrtf(deg);
        float s = sv[i];
        dinv[i] = di; tval[i] = s * di;
        out[i] = s / deg + c + b_fc[0];
    }
}
__global__ void fb_scatter(const int* __restrict__ src, const int* __restrict__ dst,
                           const float* __restrict__ tval, const float* __restrict__ dinv,
                           float* __restrict__ out, int E) {
    int stride = gridDim.x * blockDim.x;
    for (int e = blockIdx.x * blockDim.x + threadIdx.x; e < E; e += stride) {
        int si = src[e], di = dst[e];
        atomicAdd(&out[di], tval[si] * dinv[di]);
    }
}

extern "C" void kernel_launch(void* const* d_in, const int* in_sizes, int n_in,
                              void* d_out, int out_size, void* d_ws, size_t ws_size,
                              hipStream_t stream) {
    const float* x      = (const float*)d_in[0];
    const int*   ei     = (const int*)d_in[1];
    const float* Wm     = (const float*)d_in[2];
    const float* b_conv = (const float*)d_in[3];
    const float* W_fc   = (const float*)d_in[4];
    const float* b_fc   = (const float*)d_in[5];
    float* out = (float*)d_out;

    const int N = in_sizes[0] / DF;   // 100000
    const int E = in_sizes[1] / 2;    // 3200000
    const int* src = ei;
    const int* dst = ei + E;

    const int P   = (N + 255) >> PBITS;       // 391
    const int Epw = (E + WB - 1) / WB;        // 6250

    char* ws = (char*)d_ws;
    unsigned* bars = (unsigned*)ws;                      // 16 u32 (use 2)
    float* sv   = (float*)(ws + 64);                     // N
    float* dinv = sv + N;                                // N
    float* tval = dinv + N;                              // N
    unsigned* runStart = (unsigned*)(tval + N);          // (P+1)*WB
    unsigned* sorted   = runStart + (size_t)(P + 1) * WB; // WB*Epw

    const size_t need = 64 + ((size_t)3 * N + (size_t)(P + 1) * WB + (size_t)WB * Epw) * 4;
    const size_t shbytes = (size_t)Epw * 10 + (size_t)(2 * P + 2) * 4 + 64;

    // residency guards for the grid barrier
    int maxBlocksPerCU = 0, numCU = 0;
    bool occ_ok = false;
    if (hipOccupancyMaxActiveBlocksPerMultiprocessor(&maxBlocksPerCU, mega_kernel, TPB, shbytes)
            == hipSuccess &&
        hipDeviceGetAttribute(&numCU, hipDeviceAttributeMultiprocessorCount, 0) == hipSuccess)
        occ_ok = ((long)maxBlocksPerCU * numCU >= NBLK);

    if (P <= PMAX && Epw >= TPB && ws_size >= need && shbytes <= 160 * 1024 && occ_ok) {
        hipMemsetAsync(bars, 0, 64, stream);
        mega_kernel<<<NBLK, TPB, shbytes, stream>>>(x, src, dst, Wm, b_conv, W_fc, b_fc,
                                                    sv, dinv, tval, runStart, sorted, bars,
                                                    out, N, E, P, Epw);
    } else {
        unsigned* fcnt = (unsigned*)(tval + N);
        hipMemsetAsync(fcnt, 0, (size_t)N * 4, stream);
        sval_kernel<<<2048, 256, 0, stream>>>(x, Wm, W_fc, sv, N);
        fb_count<<<2048, 256, 0, stream>>>(dst, fcnt, E);
        fb_node<<<(N + 255) / 256, 256, 0, stream>>>(fcnt, sv, b_conv, W_fc, b_fc, dinv, tval, out, N);
        fb_scatter<<<2048, 256, 0, stream>>>(src, dst, tval, dinv, out, E);
    }
}

// Round 6
// 116.073 us; speedup vs baseline: 2.6700x; 2.6700x over previous
//
#include <hip/hip_runtime.h>

#define DF 256
#define HID 16
#define WB 1024         // sort slices (= sort grid)
#define STPB 512        // sort threads/block
#define WTPB 1024       // walk threads/block (16 waves)
#define PBITS 8         // partition = 256 nodes
#define PMAX 512        // scan width limit

// ---------------- K1: s[i] = x[i] . (W @ W_fc) ----------------
__global__ void sval_kernel(const float* __restrict__ x, const float* __restrict__ Wm,
                            const float* __restrict__ W_fc, float* __restrict__ sv, int N) {
    __shared__ float wl[DF];
    int k = threadIdx.x;  // 256 threads
    float a = 0.f;
#pragma unroll
    for (int j = 0; j < HID; ++j) a += Wm[k * HID + j] * W_fc[j];
    wl[k] = a;
    __syncthreads();
    int lane = threadIdx.x & 63;
    int wid = threadIdx.x >> 6;
    float4 wv = reinterpret_cast<const float4*>(wl)[lane];
    for (int row = blockIdx.x * 4 + wid; row < N; row += gridDim.x * 4) {
        float4 xv = reinterpret_cast<const float4*>(x + (size_t)row * DF)[lane];
        float acc = xv.x * wv.x + xv.y * wv.y + xv.z * wv.z + xv.w * wv.w;
#pragma unroll
        for (int off = 32; off > 0; off >>= 1) acc += __shfl_xor(acc, off, 64);
        if (lane == 0) sv[row] = acc;
    }
}

// ---------------- K2: block-local counting sort (2-read-pass, wave scan) ----------------
__global__ void sort_kernel(const int* __restrict__ src, const int* __restrict__ dst,
                            unsigned* __restrict__ runStart, unsigned* __restrict__ sorted,
                            int P, int E, int Epw) {
    extern __shared__ unsigned smem[];
    unsigned* sortl = smem;            // Epw  (sorted slice)
    unsigned* cur   = sortl + Epw;     // P    (hist -> scatter cursor)
    unsigned* offs  = cur + P;         // P+1
    unsigned* wsum  = offs + P + 1;    // 8

    const int w = blockIdx.x;
    const size_t e0 = (size_t)w * Epw;
    int m = (int)((size_t)E > e0 ? (size_t)E - e0 : 0);
    if (m > Epw) m = Epw;

    // pass 1: histogram of dst partitions
    for (int i = threadIdx.x; i < P; i += STPB) cur[i] = 0;
    __syncthreads();
    for (int i = threadIdx.x; i < m; i += STPB)
        atomicAdd(&cur[((unsigned)dst[e0 + i]) >> PBITS], 1u);
    __syncthreads();

    // exclusive scan over cur[0..P) : wave shfl scan + 8-wave combine (3 barriers)
    {
        int t = threadIdx.x, lane = t & 63, wid = t >> 6;
        unsigned v = (t < P) ? cur[t] : 0u;
        unsigned xi = v;
#pragma unroll
        for (int off = 1; off < 64; off <<= 1) {
            unsigned u = __shfl_up(xi, off, 64);
            if (lane >= off) xi += u;
        }
        if (lane == 63) wsum[wid] = xi;
        __syncthreads();
        if (t < 8) {
            unsigned u = wsum[t];
#pragma unroll
            for (int off = 1; off < 8; off <<= 1) {
                unsigned uu = __shfl_up(u, off, 64);
                if (t >= off) u += uu;
            }
            wsum[t] = u;  // inclusive scan of wave sums
        }
        __syncthreads();
        unsigned excl = xi - v + (wid ? wsum[wid - 1] : 0u);
        if (t < P) offs[t] = excl;
        if (t == 0) offs[P] = wsum[7];
        __syncthreads();
        for (int i = threadIdx.x; i < P; i += STPB) cur[i] = offs[i];
    }
    __syncthreads();

    // pass 2: re-read edges, scatter into LDS sorted order
    for (int i = threadIdx.x; i < m; i += STPB) {
        unsigned s = (unsigned)src[e0 + i];
        unsigned d = (unsigned)dst[e0 + i];
        unsigned slot = atomicAdd(&cur[d >> PBITS], 1u);
        sortl[slot] = (s << PBITS) | (d & 255u);
    }
    __syncthreads();
    // coalesced write-out
    for (int i = threadIdx.x; i < m; i += STPB) sorted[e0 + i] = sortl[i];
    for (int pp = threadIdx.x; pp <= P; pp += STPB) runStart[(size_t)pp * WB + w] = offs[pp];
}

// ---------------- K3: per-partition degree (wave-per-run) -> dinv, tval ----------------
__global__ void degfin_kernel(const unsigned* __restrict__ sorted, const unsigned* __restrict__ runStart,
                              const float* __restrict__ sv, float* __restrict__ dinv,
                              float* __restrict__ tval, int N, int Epw) {
    __shared__ unsigned s0a[WB], s1a[WB];
    __shared__ unsigned dc[256];
    const int p = blockIdx.x;
    for (int i = threadIdx.x; i < WB; i += WTPB) {
        s0a[i] = runStart[(size_t)p * WB + i];
        s1a[i] = runStart[(size_t)(p + 1) * WB + i];
    }
    if (threadIdx.x < 256) dc[threadIdx.x] = 0u;
    __syncthreads();
    const int wave = threadIdx.x >> 6, lane = threadIdx.x & 63;
    for (int w = wave; w < WB; w += (WTPB / 64)) {
        unsigned s0 = s0a[w], s1 = s1a[w];
        const unsigned* base = sorted + (size_t)w * Epw;
        for (unsigned j = s0 + lane; j < s1; j += 64)
            atomicAdd(&dc[base[j] & 255u], 1u);
    }
    __syncthreads();
    if (threadIdx.x < 256) {
        int i = (p << PBITS) + (int)threadIdx.x;
        if (i < N) {
            float deg = 1.0f + (float)dc[threadIdx.x];
            float di = rsqrtf(deg);
            dinv[i] = di;
            tval[i] = sv[i] * di;
        }
    }
}

// ---------------- K4: per-partition reduce (wave-per-run) -> out ----------------
__global__ void reduce_kernel(const unsigned* __restrict__ sorted, const unsigned* __restrict__ runStart,
                              const float* __restrict__ tval, const float* __restrict__ dinv,
                              const float* __restrict__ sv, const float* __restrict__ b_conv,
                              const float* __restrict__ W_fc, const float* __restrict__ b_fc,
                              float* __restrict__ out, int N, int Epw) {
    __shared__ unsigned s0a[WB], s1a[WB];
    __shared__ float facc[256];
    const int p = blockIdx.x;
    for (int i = threadIdx.x; i < WB; i += WTPB) {
        s0a[i] = runStart[(size_t)p * WB + i];
        s1a[i] = runStart[(size_t)(p + 1) * WB + i];
    }
    if (threadIdx.x < 256) facc[threadIdx.x] = 0.f;
    __syncthreads();
    const int wave = threadIdx.x >> 6, lane = threadIdx.x & 63;
    for (int w = wave; w < WB; w += (WTPB / 64)) {
        unsigned s0 = s0a[w], s1 = s1a[w];
        const unsigned* base = sorted + (size_t)w * Epw;
        for (unsigned j = s0 + lane; j < s1; j += 64) {
            unsigned e = base[j];
            atomicAdd(&facc[e & 255u], tval[e >> PBITS]);
        }
    }
    __syncthreads();
    if (threadIdx.x < 256) {
        int i = (p << PBITS) + (int)threadIdx.x;
        if (i < N) {
            float c = 0.f;
#pragma unroll
            for (int j = 0; j < HID; ++j) c += b_conv[j] * W_fc[j];
            float di = dinv[i];
            out[i] = sv[i] * di * di + c + b_fc[0] + di * facc[threadIdx.x];
        }
    }
}

// ---------------- fallback: proven global-atomic path ----------------
__global__ void fb_count(const int* __restrict__ dst, unsigned* __restrict__ cnt, int E) {
    int stride = gridDim.x * blockDim.x;
    for (int e = blockIdx.x * blockDim.x + threadIdx.x; e < E; e += stride)
        atomicAdd(&cnt[dst[e]], 1u);
}
__global__ void fb_node(const unsigned* __restrict__ cnt, const float* __restrict__ sv,
                        const float* __restrict__ b_conv, const float* __restrict__ W_fc,
                        const float* __restrict__ b_fc, float* __restrict__ dinv,
                        float* __restrict__ tval, float* __restrict__ out, int N) {
    int i = blockIdx.x * blockDim.x + threadIdx.x;
    if (i < N) {
        float c = 0.f;
#pragma unroll
        for (int j = 0; j < HID; ++j) c += b_conv[j] * W_fc[j];
        float deg = 1.0f + (float)cnt[i];
        float di = rsqrtf(deg);
        float s = sv[i];
        dinv[i] = di; tval[i] = s * di;
        out[i] = s / deg + c + b_fc[0];
    }
}
__global__ void fb_scatter(const int* __restrict__ src, const int* __restrict__ dst,
                           const float* __restrict__ tval, const float* __restrict__ dinv,
                           float* __restrict__ out, int E) {
    int stride = gridDim.x * blockDim.x;
    for (int e = blockIdx.x * blockDim.x + threadIdx.x; e < E; e += stride) {
        int si = src[e], di = dst[e];
        atomicAdd(&out[di], tval[si] * dinv[di]);
    }
}

extern "C" void kernel_launch(void* const* d_in, const int* in_sizes, int n_in,
                              void* d_out, int out_size, void* d_ws, size_t ws_size,
                              hipStream_t stream) {
    const float* x      = (const float*)d_in[0];
    const int*   ei     = (const int*)d_in[1];
    const float* Wm     = (const float*)d_in[2];
    const float* b_conv = (const float*)d_in[3];
    const float* W_fc   = (const float*)d_in[4];
    const float* b_fc   = (const float*)d_in[5];
    float* out = (float*)d_out;

    const int N = in_sizes[0] / DF;   // 100000
    const int E = in_sizes[1] / 2;    // 3200000
    const int* src = ei;
    const int* dst = ei + E;

    const int P   = (N + 255) >> PBITS;       // 391
    const int Epw = (E + WB - 1) / WB;        // 3125

    char* ws = (char*)d_ws;
    float* sv   = (float*)ws;                               // N
    float* dinv = sv + N;                                   // N
    float* tval = dinv + N;                                 // N
    unsigned* runStart = (unsigned*)(tval + N);             // (P+1)*WB
    unsigned* sorted   = runStart + (size_t)(P + 1) * WB;   // WB*Epw

    const size_t need = ((size_t)3 * N + (size_t)(P + 1) * WB + (size_t)WB * Epw) * 4;
    const size_t shbytes = ((size_t)Epw + 2 * (size_t)P + 9) * 4 + 64;

    if (P >= 1 && P <= PMAX && N <= (1 << 24) && ws_size >= need && shbytes <= 60 * 1024) {
        sval_kernel<<<2048, 256, 0, stream>>>(x, Wm, W_fc, sv, N);
        sort_kernel<<<WB, STPB, shbytes, stream>>>(src, dst, runStart, sorted, P, E, Epw);
        degfin_kernel<<<P, WTPB, 0, stream>>>(sorted, runStart, sv, dinv, tval, N, Epw);
        reduce_kernel<<<P, WTPB, 0, stream>>>(sorted, runStart, tval, dinv, sv,
                                              b_conv, W_fc, b_fc, out, N, Epw);
    } else {
        unsigned* fcnt = (unsigned*)(tval + N);
        hipMemsetAsync(fcnt, 0, (size_t)N * 4, stream);
        sval_kernel<<<2048, 256, 0, stream>>>(x, Wm, W_fc, sv, N);
        fb_count<<<2048, 256, 0, stream>>>(dst, fcnt, E);
        fb_node<<<(N + 255) / 256, 256, 0, stream>>>(fcnt, sv, b_conv, W_fc, b_fc, dinv, tval, out, N);
        fb_scatter<<<2048, 256, 0, stream>>>(src, dst, tval, dinv, out, E);
    }
}

// Round 7
// 90.956 us; speedup vs baseline: 3.4073x; 1.2761x over previous
//
#include <hip/hip_runtime.h>

#define DF 256
#define HID 16
#define WB 512          // edge slices (= hist/scatter grid)
#define PBITS 8         // partition = 256 nodes
#define PMAX 512        // scan width limit (P <= 512)

// ---------- K1: per-slice partition histogram (transposed out) + fused sval ----------
__global__ void __launch_bounds__(512)
hist_sval_kernel(const float* __restrict__ x, const int* __restrict__ dst,
                 const float* __restrict__ Wm, const float* __restrict__ W_fc,
                 unsigned* __restrict__ cntT, float* __restrict__ sv,
                 int N, int E, int P, int Epw) {
    __shared__ unsigned h[PMAX];
    for (int i = threadIdx.x; i < P; i += blockDim.x) h[i] = 0u;
    __syncthreads();
    const int w = blockIdx.x;
    const size_t e0 = (size_t)w * Epw;
    int m = (int)((size_t)E > e0 ? (size_t)E - e0 : 0);
    if (m > Epw) m = Epw;
    for (int i = threadIdx.x; i < m; i += blockDim.x)
        atomicAdd(&h[((unsigned)dst[e0 + i]) >> PBITS], 1u);
    __syncthreads();
    for (int p = threadIdx.x; p < P; p += blockDim.x)
        cntT[(size_t)p * WB + w] = h[p];   // transposed: row p is contiguous over w

    // fused sval: s[row] = x[row] . (Wm @ W_fc), w-vector in registers per wave
    const int lane = threadIdx.x & 63, wid = threadIdx.x >> 6;  // 8 waves
    float a0 = 0.f, a1 = 0.f, a2 = 0.f, a3 = 0.f;
    const float* wrow = Wm + (size_t)(lane * 4) * HID;
#pragma unroll
    for (int j = 0; j < HID; ++j) {
        float f = W_fc[j];
        a0 += wrow[j] * f;
        a1 += wrow[HID + j] * f;
        a2 += wrow[2 * HID + j] * f;
        a3 += wrow[3 * HID + j] * f;
    }
    for (int row = blockIdx.x * 8 + wid; row < N; row += WB * 8) {
        float4 xv = reinterpret_cast<const float4*>(x + (size_t)row * DF)[lane];
        float acc = xv.x * a0 + xv.y * a1 + xv.z * a2 + xv.w * a3;
#pragma unroll
        for (int off = 32; off > 0; off >>= 1) acc += __shfl_xor(acc, off, 64);
        if (lane == 0) sv[row] = acc;
    }
}

// ---------- K2a: per-partition exclusive scan across slices (coalesced row) ----------
__global__ void __launch_bounds__(WB)
rowscan_kernel(unsigned* __restrict__ cntT, unsigned* __restrict__ rowTotal) {
    __shared__ unsigned wsum[8];
    const int p = blockIdx.x, t = threadIdx.x;
    const int lane = t & 63, wid = t >> 6;
    unsigned v = cntT[(size_t)p * WB + t];
    unsigned xi = v;
#pragma unroll
    for (int off = 1; off < 64; off <<= 1) {
        unsigned u = __shfl_up(xi, off, 64);
        if (lane >= off) xi += u;
    }
    if (lane == 63) wsum[wid] = xi;
    __syncthreads();
    if (t < 8) {
        unsigned u = wsum[t];
#pragma unroll
        for (int off = 1; off < 8; off <<= 1) {
            unsigned uu = __shfl_up(u, off, 64);
            if (t >= off) u += uu;
        }
        wsum[t] = u;
    }
    __syncthreads();
    unsigned base = wid ? wsum[wid - 1] : 0u;
    cntT[(size_t)p * WB + t] = xi - v + base;   // exclusive within row
    if (t == 0) rowTotal[p] = wsum[7];
}

// ---------- K2b: exclusive scan over partition totals ----------
__global__ void __launch_bounds__(PMAX)
partscan_kernel(const unsigned* __restrict__ rowTotal, unsigned* __restrict__ partBase,
                int P, int E) {
    __shared__ unsigned wsum[8];
    const int t = threadIdx.x, lane = t & 63, wid = t >> 6;
    unsigned v = (t < P) ? rowTotal[t] : 0u;
    unsigned xi = v;
#pragma unroll
    for (int off = 1; off < 64; off <<= 1) {
        unsigned u = __shfl_up(xi, off, 64);
        if (lane >= off) xi += u;
    }
    if (lane == 63) wsum[wid] = xi;
    __syncthreads();
    if (t < 8) {
        unsigned u = wsum[t];
#pragma unroll
        for (int off = 1; off < 8; off <<= 1) {
            unsigned uu = __shfl_up(u, off, 64);
            if (t >= off) u += uu;
        }
        wsum[t] = u;
    }
    __syncthreads();
    unsigned base = wid ? wsum[wid - 1] : 0u;
    if (t < P) partBase[t] = xi - v + base;
    if (t == 0) partBase[P] = (unsigned)E;
}

// ---------- K3: scatter edges into partition-contiguous order ----------
__global__ void __launch_bounds__(512)
binscatter_kernel(const int* __restrict__ src, const int* __restrict__ dst,
                  const unsigned* __restrict__ cntT, const unsigned* __restrict__ partBase,
                  unsigned* __restrict__ sorted, int P, int E, int Epw) {
    __shared__ unsigned cur[PMAX];
    const int w = blockIdx.x;
    for (int p = threadIdx.x; p < P; p += blockDim.x)
        cur[p] = partBase[p] + cntT[(size_t)p * WB + w];
    __syncthreads();
    const size_t e0 = (size_t)w * Epw;
    int m = (int)((size_t)E > e0 ? (size_t)E - e0 : 0);
    if (m > Epw) m = Epw;
    for (int i = threadIdx.x; i < m; i += blockDim.x) {
        unsigned s = (unsigned)src[e0 + i];
        unsigned d = (unsigned)dst[e0 + i];
        unsigned slot = atomicAdd(&cur[d >> PBITS], 1u);
        sorted[slot] = (s << PBITS) | (d & 255u);
    }
}

// ---------- K4: linear per-partition degree walk -> dinv, tval ----------
__global__ void __launch_bounds__(1024)
degfin_kernel(const unsigned* __restrict__ sorted, const unsigned* __restrict__ partBase,
              const float* __restrict__ sv, float* __restrict__ dinv,
              float* __restrict__ tval, int N) {
    __shared__ unsigned dc[256];
    const int p = blockIdx.x;
    if (threadIdx.x < 256) dc[threadIdx.x] = 0u;
    __syncthreads();
    const unsigned b0 = partBase[p], b1 = partBase[p + 1];
    for (unsigned j = b0 + threadIdx.x; j < b1; j += blockDim.x)
        atomicAdd(&dc[sorted[j] & 255u], 1u);
    __syncthreads();
    if (threadIdx.x < 256) {
        int i = (p << PBITS) + (int)threadIdx.x;
        if (i < N) {
            float deg = 1.0f + (float)dc[threadIdx.x];
            float di = rsqrtf(deg);
            dinv[i] = di;
            tval[i] = sv[i] * di;
        }
    }
}

// ---------- K5: linear per-partition value walk -> out ----------
__global__ void __launch_bounds__(1024)
reduce_kernel(const unsigned* __restrict__ sorted, const unsigned* __restrict__ partBase,
              const float* __restrict__ tval, const float* __restrict__ dinv,
              const float* __restrict__ sv, const float* __restrict__ b_conv,
              const float* __restrict__ W_fc, const float* __restrict__ b_fc,
              float* __restrict__ out, int N) {
    __shared__ float facc[256];
    const int p = blockIdx.x;
    if (threadIdx.x < 256) facc[threadIdx.x] = 0.f;
    __syncthreads();
    const unsigned b0 = partBase[p], b1 = partBase[p + 1];
    for (unsigned j = b0 + threadIdx.x; j < b1; j += blockDim.x) {
        unsigned e = sorted[j];
        atomicAdd(&facc[e & 255u], tval[e >> PBITS]);
    }
    __syncthreads();
    if (threadIdx.x < 256) {
        int i = (p << PBITS) + (int)threadIdx.x;
        if (i < N) {
            float c = 0.f;
#pragma unroll
            for (int j = 0; j < HID; ++j) c += b_conv[j] * W_fc[j];
            float di = dinv[i];
            out[i] = sv[i] * di * di + c + b_fc[0] + di * facc[threadIdx.x];
        }
    }
}

// ---------- fallback: proven global-atomic path ----------
__global__ void fb_sval(const float* __restrict__ x, const float* __restrict__ Wm,
                        const float* __restrict__ W_fc, float* __restrict__ sv, int N) {
    __shared__ float wl[DF];
    int k = threadIdx.x;
    float a = 0.f;
#pragma unroll
    for (int j = 0; j < HID; ++j) a += Wm[k * HID + j] * W_fc[j];
    wl[k] = a;
    __syncthreads();
    int lane = threadIdx.x & 63, wid = threadIdx.x >> 6;
    float4 wv = reinterpret_cast<const float4*>(wl)[lane];
    for (int row = blockIdx.x * 4 + wid; row < N; row += gridDim.x * 4) {
        float4 xv = reinterpret_cast<const float4*>(x + (size_t)row * DF)[lane];
        float acc = xv.x * wv.x + xv.y * wv.y + xv.z * wv.z + xv.w * wv.w;
#pragma unroll
        for (int off = 32; off > 0; off >>= 1) acc += __shfl_xor(acc, off, 64);
        if (lane == 0) sv[row] = acc;
    }
}
__global__ void fb_count(const int* __restrict__ dst, unsigned* __restrict__ cnt, int E) {
    int stride = gridDim.x * blockDim.x;
    for (int e = blockIdx.x * blockDim.x + threadIdx.x; e < E; e += stride)
        atomicAdd(&cnt[dst[e]], 1u);
}
__global__ void fb_node(const unsigned* __restrict__ cnt, const float* __restrict__ sv,
                        const float* __restrict__ b_conv, const float* __restrict__ W_fc,
                        const float* __restrict__ b_fc, float* __restrict__ dinv,
                        float* __restrict__ tval, float* __restrict__ out, int N) {
    int i = blockIdx.x * blockDim.x + threadIdx.x;
    if (i < N) {
        float c = 0.f;
#pragma unroll
        for (int j = 0; j < HID; ++j) c += b_conv[j] * W_fc[j];
        float deg = 1.0f + (float)cnt[i];
        float di = rsqrtf(deg);
        float s = sv[i];
        dinv[i] = di; tval[i] = s * di;
        out[i] = s / deg + c + b_fc[0];
    }
}
__global__ void fb_scatter(const int* __restrict__ src, const int* __restrict__ dst,
                           const float* __restrict__ tval, const float* __restrict__ dinv,
                           float* __restrict__ out, int E) {
    int stride = gridDim.x * blockDim.x;
    for (int e = blockIdx.x * blockDim.x + threadIdx.x; e < E; e += stride) {
        int si = src[e], di = dst[e];
        atomicAdd(&out[di], tval[si] * dinv[di]);
    }
}

extern "C" void kernel_launch(void* const* d_in, const int* in_sizes, int n_in,
                              void* d_out, int out_size, void* d_ws, size_t ws_size,
                              hipStream_t stream) {
    const float* x      = (const float*)d_in[0];
    const int*   ei     = (const int*)d_in[1];
    const float* Wm     = (const float*)d_in[2];
    const float* b_conv = (const float*)d_in[3];
    const float* W_fc   = (const float*)d_in[4];
    const float* b_fc   = (const float*)d_in[5];
    float* out = (float*)d_out;

    const int N = in_sizes[0] / DF;   // 100000
    const int E = in_sizes[1] / 2;    // 3200000
    const int* src = ei;
    const int* dst = ei + E;

    const int P   = (N + 255) >> PBITS;       // 391
    const int Epw = (E + WB - 1) / WB;        // 6250

    char* ws = (char*)d_ws;
    float* sv   = (float*)ws;                               // N
    float* dinv = sv + N;                                   // N
    float* tval = dinv + N;                                 // N
    unsigned* cntT     = (unsigned*)(tval + N);             // P*WB
    unsigned* rowTotal = cntT + (size_t)P * WB;             // 512
    unsigned* partBase = rowTotal + 512;                    // P+1 (pad 520)
    unsigned* sorted   = partBase + 520;                    // E

    const size_t need = ((size_t)3 * N + (size_t)P * WB + 512 + 520 + (size_t)E) * 4;

    if (P >= 1 && P <= PMAX && N <= (1 << 23) && ws_size >= need) {
        hist_sval_kernel<<<WB, 512, 0, stream>>>(x, dst, Wm, W_fc, cntT, sv, N, E, P, Epw);
        rowscan_kernel<<<P, WB, 0, stream>>>(cntT, rowTotal);
        partscan_kernel<<<1, PMAX, 0, stream>>>(rowTotal, partBase, P, E);
        binscatter_kernel<<<WB, 512, 0, stream>>>(src, dst, cntT, partBase, sorted, P, E, Epw);
        degfin_kernel<<<P, 1024, 0, stream>>>(sorted, partBase, sv, dinv, tval, N);
        reduce_kernel<<<P, 1024, 0, stream>>>(sorted, partBase, tval, dinv, sv,
                                              b_conv, W_fc, b_fc, out, N);
    } else {
        unsigned* fcnt = (unsigned*)(tval + N);
        hipMemsetAsync(fcnt, 0, (size_t)N * 4, stream);
        fb_sval<<<2048, 256, 0, stream>>>(x, Wm, W_fc, sv, N);
        fb_count<<<2048, 256, 0, stream>>>(dst, fcnt, E);
        fb_node<<<(N + 255) / 256, 256, 0, stream>>>(fcnt, sv, b_conv, W_fc, b_fc, dinv, tval, out, N);
        fb_scatter<<<2048, 256, 0, stream>>>(src, dst, tval, dinv, out, E);
    }
}